// Round 8
// baseline (197.562 us; speedup 1.0000x reference)
//
#include <hip/hip_runtime.h>
#include <math.h>

typedef float        f32x4 __attribute__((ext_vector_type(4)));
typedef unsigned int u32x4 __attribute__((ext_vector_type(4)));

static constexpr int DIM    = 33;
static constexpr int LUT_N  = DIM * DIM * DIM;          // 35937
static constexpr int HW     = 1024 * 1024;
static constexpr int BATCH  = 8;
static constexpr long NPIX  = (long)BATCH * HW;         // 8388608
static constexpr long NTASK = NPIX / 4;                 // fallback only

static constexpr size_t LDS_BYTES = 143872;             // 128B-rounded >= LUT_N*4

// apply geometry: 256 blocks x 1024 threads == HW/4 threads exactly.
static constexpr int ABLK = 256;
static constexpr int ATHR = 1024;

// ---------------------------------------------------------------------------
// helpers — VOLATILE vector IO.
// Why volatile: R3/R6/R7 all showed the compiler sinking prefetch loads down
// to their use (VGPR 44/64/52), recreating the serial chain
//   wait-stores -> load -> wait-load -> gather -> decode -> store
// where the in-order vmcnt retirement puts the PREVIOUS stores' HBM acks on
// the critical path. Volatile ops keep source order (loads stay hoisted,
// depth-2 ahead) while remaining visible to the compiler's waitcnt insertion,
// so the wait for image it's pixels is a counted vmcnt ~2 iterations after
// issue — store acks never block the loop.
// ---------------------------------------------------------------------------
__device__ __forceinline__ f32x4 vld4(const float* p) {
    return *(const volatile f32x4*)p;
}
__device__ __forceinline__ void vst4(float* p, f32x4 v) {
    *(volatile f32x4*)p = v;
}
__device__ __forceinline__ float d_r(unsigned n) { return (float)(n & 1023u); }
__device__ __forceinline__ float d_g(unsigned n) { return (float)((n >> 10) & 1023u); }
__device__ __forceinline__ float d_b(unsigned n) { return (float)(n >> 20); }

// ---------------------------------------------------------------------------
// gather + decode + weighted trilinear + store for one image's 4-pixel quad
// ---------------------------------------------------------------------------
__device__ __forceinline__ void apply_image(const unsigned* __restrict__ sl,
                                            f32x4 rc, f32x4 gc, f32x4 bc,
                                            float* __restrict__ o,
                                            float inv, float mn) {
    unsigned n[4][8];
    float fr[4], fg[4], fb[4];
#pragma unroll
    for (int i = 0; i < 4; ++i) {
        const float scale = (float)(DIM - 1);
        float rs = rc[i] * scale, gs = gc[i] * scale, bs = bc[i] * scale;
        int ir = (int)rs; ir = ir < 0 ? 0 : (ir > DIM - 2 ? DIM - 2 : ir);
        int ig = (int)gs; ig = ig < 0 ? 0 : (ig > DIM - 2 ? DIM - 2 : ig);
        int ib = (int)bs; ib = ib < 0 ? 0 : (ib > DIM - 2 ? DIM - 2 : ib);
        fr[i] = rs - (float)ir;
        fg[i] = gs - (float)ig;
        fb[i] = bs - (float)ib;
        int s = ib * (DIM * DIM) + ig * DIM + ir;
        n[i][0] = sl[s];                     n[i][1] = sl[s + 1];
        n[i][2] = sl[s + DIM];               n[i][3] = sl[s + DIM + 1];
        n[i][4] = sl[s + DIM * DIM];         n[i][5] = sl[s + DIM * DIM + 1];
        n[i][6] = sl[s + DIM * DIM + DIM];   n[i][7] = sl[s + DIM * DIM + DIM + 1];
    }

    f32x4 orv, ogv, obv;
#pragma unroll
    for (int i = 0; i < 4; ++i) {
        float frv = fr[i], fgv = fg[i], fbv = fb[i];
        float frc = 1.0f - frv, fgc = 1.0f - fgv, fbc = 1.0f - fbv;
        float w00 = fbc * fgc, w01 = fbc * fgv;
        float w10 = fbv * fgc, w11 = fbv * fgv;
        float u0 = w00 * frc, u1 = w00 * frv;
        float u2 = w01 * frc, u3 = w01 * frv;
        float u4 = w10 * frc, u5 = w10 * frv;
        float u6 = w11 * frc, u7 = w11 * frv;

        float qr = u0 * d_r(n[i][0]);
        qr = fmaf(u1, d_r(n[i][1]), qr);
        qr = fmaf(u2, d_r(n[i][2]), qr);
        qr = fmaf(u3, d_r(n[i][3]), qr);
        qr = fmaf(u4, d_r(n[i][4]), qr);
        qr = fmaf(u5, d_r(n[i][5]), qr);
        qr = fmaf(u6, d_r(n[i][6]), qr);
        qr = fmaf(u7, d_r(n[i][7]), qr);

        float qg = u0 * d_g(n[i][0]);
        qg = fmaf(u1, d_g(n[i][1]), qg);
        qg = fmaf(u2, d_g(n[i][2]), qg);
        qg = fmaf(u3, d_g(n[i][3]), qg);
        qg = fmaf(u4, d_g(n[i][4]), qg);
        qg = fmaf(u5, d_g(n[i][5]), qg);
        qg = fmaf(u6, d_g(n[i][6]), qg);
        qg = fmaf(u7, d_g(n[i][7]), qg);

        float qb = u0 * d_b(n[i][0]);
        qb = fmaf(u1, d_b(n[i][1]), qb);
        qb = fmaf(u2, d_b(n[i][2]), qb);
        qb = fmaf(u3, d_b(n[i][3]), qb);
        qb = fmaf(u4, d_b(n[i][4]), qb);
        qb = fmaf(u5, d_b(n[i][5]), qb);
        qb = fmaf(u6, d_b(n[i][6]), qb);
        qb = fmaf(u7, d_b(n[i][7]), qb);

        orv[i] = fmaf(qr, inv, mn);
        ogv[i] = fmaf(qg, inv, mn);
        obv[i] = fmaf(qb, inv, mn);
    }
    vst4(o, orv);
    vst4(o + HW, ogv);
    vst4(o + 2 * (size_t)HW, obv);
}

// ---------------------------------------------------------------------------
// Fused single kernel, depth-2 volatile-pinned load pipeline:
//   prologue: volatile loads of img 0 & 1 (latency hides under stages A+B)
//   A: per-block LUT min/max (L2-resident; order-independent => exact)
//   B: quantize LUT to u10 r|g<<10|b<<20 into LDS
//   C: 8 x { volatile-load img it+2 | gather+decode+volatile-store img it }
//   __launch_bounds__(1024,4): LDS caps at 1 block/CU = 4 waves/SIMD anyway;
//   declares it so the VGPR cap is 128 and the ~3-image payload stays resident.
// ---------------------------------------------------------------------------
__global__ __launch_bounds__(1024, 4) void lut_fused(
    const float* __restrict__ x, const float* __restrict__ lut,
    float* __restrict__ out) {
    extern __shared__ unsigned sl[];
    const int t = threadIdx.x;

    const int gtid = blockIdx.x * ATHR + t;          // [0, 2^18)
    const size_t hw4 = (size_t)gtid * 4;             // [0, HW)
    const float* xp = x + hw4;
    float*       op = out + hw4;

    f32x4 ar[BATCH], ag[BATCH], ab[BATCH];
    // prologue: img 0 and 1 issue now (volatile: cannot be sunk)
#pragma unroll
    for (int it = 0; it < 2; ++it) {
        const float* xi = xp + (size_t)it * (3 * (size_t)HW);
        ar[it] = vld4(xi);
        ag[it] = vld4(xi + HW);
        ab[it] = vld4(xi + 2 * (size_t)HW);
    }

    // ---- stage A: block-wide min/max over all 3*LUT_N floats ----
    float vmin = 1e30f, vmax = -1e30f;
    {
        const f32x4* l4 = (const f32x4*)lut;        // base is 16B-aligned
        const int NV = (3 * LUT_N) / 4;             // 26952 full float4s
#pragma unroll 4
        for (int i = t; i < NV; i += 1024) {
            f32x4 v = l4[i];
            vmin = fminf(vmin, fminf(fminf(v[0], v[1]), fminf(v[2], v[3])));
            vmax = fmaxf(vmax, fmaxf(fmaxf(v[0], v[1]), fmaxf(v[2], v[3])));
        }
        if (t < 3) {                                 // tail elems 107808..107810
            float v = lut[NV * 4 + t];
            vmin = fminf(vmin, v);
            vmax = fmaxf(vmax, v);
        }
    }
#pragma unroll
    for (int off = 32; off > 0; off >>= 1) {
        vmin = fminf(vmin, __shfl_down(vmin, off));
        vmax = fmaxf(vmax, __shfl_down(vmax, off));
    }
    float* sf = (float*)sl;
    if ((t & 63) == 0) { sf[t >> 6] = vmin; sf[16 + (t >> 6)] = vmax; }
    __syncthreads();
    float mn = sf[0], mx = sf[16];
#pragma unroll
    for (int k = 1; k < 16; ++k) {
        mn = fminf(mn, sf[k]);
        mx = fmaxf(mx, sf[16 + k]);
    }
    __syncthreads();  // all threads hold mn/mx; sl reusable

    float range = mx - mn;
    if (range < 1e-20f) range = 1e-20f;
    const float qscale = 1023.0f / range;
    const float inv    = range * (1.0f / 1023.0f);

    // ---- stage B: quantize LUT into LDS (coalesced scalar, L2-hot) ----
#pragma unroll 2
    for (int i = t; i < LUT_N; i += 1024) {
        float r = lut[i], g = lut[LUT_N + i], b = lut[2 * LUT_N + i];
        unsigned qr = (unsigned)__float2int_rn((r - mn) * qscale);
        unsigned qg = (unsigned)__float2int_rn((g - mn) * qscale);
        unsigned qb = (unsigned)__float2int_rn((b - mn) * qscale);
        sl[i] = qr | (qg << 10) | (qb << 20);
    }
    __syncthreads();

    // ---- stage C: depth-2 load pipeline (volatile order = source order) ----
#pragma unroll
    for (int it = 0; it < BATCH; ++it) {
        if (it + 2 < BATCH) {
            const float* xn = xp + (size_t)(it + 2) * (3 * (size_t)HW);
            ar[it + 2] = vld4(xn);
            ag[it + 2] = vld4(xn + HW);
            ab[it + 2] = vld4(xn + 2 * (size_t)HW);
        }
        apply_image(sl, ar[it], ag[it], ab[it],
                    op + (size_t)it * (3 * (size_t)HW), inv, mn);
    }
}

// ---------------------------------------------------------------------------
// Fallback: direct SoA gathers, exact fp32 (safety net; not dispatched).
// ---------------------------------------------------------------------------
__global__ __launch_bounds__(256) void lut_apply_soa(
    const float* __restrict__ x, const float* __restrict__ lut,
    float* __restrict__ out) {
    long t = (long)blockIdx.x * 256 + threadIdx.x;
    long p = t * 4;
    int  b  = (int)(p >> 20);
    int  hw = (int)(p & (HW - 1));
    size_t base = (size_t)b * (3 * (size_t)HW) + (size_t)hw;

    float4 rv = *(const float4*)(x + base);
    float4 gv = *(const float4*)(x + base + (size_t)HW);
    float4 bv = *(const float4*)(x + base + 2 * (size_t)HW);

    float rr[4] = {rv.x, rv.y, rv.z, rv.w};
    float gg[4] = {gv.x, gv.y, gv.z, gv.w};
    float bb[4] = {bv.x, bv.y, bv.z, bv.w};
    float orr[4], org[4], orb[4];

#pragma unroll
    for (int i = 0; i < 4; ++i) {
        const float scale = (float)(DIM - 1);
        float rs = rr[i] * scale, gs = gg[i] * scale, bs = bb[i] * scale;
        int ir = (int)floorf(rs); ir = ir < 0 ? 0 : (ir > DIM - 2 ? DIM - 2 : ir);
        int ig = (int)floorf(gs); ig = ig < 0 ? 0 : (ig > DIM - 2 ? DIM - 2 : ig);
        int ib = (int)floorf(bs); ib = ib < 0 ? 0 : (ib > DIM - 2 ? DIM - 2 : ib);
        float fr = rs - (float)ir, fg = gs - (float)ig, fb = bs - (float)ib;
        int base_i = (ib * DIM + ig) * DIM + ir;
        float acc[3] = {0.f, 0.f, 0.f};
#pragma unroll
        for (int db = 0; db < 2; ++db) {
            float wb = db ? fb : 1.f - fb;
#pragma unroll
            for (int dg = 0; dg < 2; ++dg) {
                float wg = dg ? fg : 1.f - fg;
#pragma unroll
                for (int dr = 0; dr < 2; ++dr) {
                    float wr = dr ? fr : 1.f - fr;
                    int idx = base_i + (db * DIM + dg) * DIM + dr;
                    float w = wb * wg * wr;
                    acc[0] = fmaf(w, lut[idx], acc[0]);
                    acc[1] = fmaf(w, lut[LUT_N + idx], acc[1]);
                    acc[2] = fmaf(w, lut[2 * LUT_N + idx], acc[2]);
                }
            }
        }
        orr[i] = acc[0]; org[i] = acc[1]; orb[i] = acc[2];
    }

    *(float4*)(out + base)                  = make_float4(orr[0], orr[1], orr[2], orr[3]);
    *(float4*)(out + base + (size_t)HW)     = make_float4(org[0], org[1], org[2], org[3]);
    *(float4*)(out + base + 2 * (size_t)HW) = make_float4(orb[0], orb[1], orb[2], orb[3]);
}

extern "C" void kernel_launch(void* const* d_in, const int* in_sizes, int n_in,
                              void* d_out, int out_size, void* d_ws, size_t ws_size,
                              hipStream_t stream) {
    const float* lut = (const float*)d_in[0];
    const float* x   = (const float*)d_in[1];
    if (n_in >= 2 && in_sizes[0] > in_sizes[1]) {  // defensive: order swapped
        lut = (const float*)d_in[1];
        x   = (const float*)d_in[0];
    }
    float* out = (float*)d_out;
    (void)d_ws; (void)ws_size;

    // Allow >64KB dynamic LDS (gfx950 has 160 KiB). Host-side attr set,
    // idempotent, graph-capture safe.
    (void)hipFuncSetAttribute((const void*)lut_fused,
                              hipFuncAttributeMaxDynamicSharedMemorySize,
                              (int)LDS_BYTES);
    lut_fused<<<ABLK, ATHR, LDS_BYTES, stream>>>(x, lut, out);
}

// Round 9
// 189.113 us; speedup vs baseline: 1.0447x; 1.0447x over previous
//
#include <hip/hip_runtime.h>
#include <math.h>

typedef float        f32x4 __attribute__((ext_vector_type(4)));
typedef unsigned int u32x4 __attribute__((ext_vector_type(4)));

static constexpr int DIM    = 33;
static constexpr int LUT_N  = DIM * DIM * DIM;          // 35937
static constexpr int HW     = 1024 * 1024;
static constexpr int BATCH  = 8;
static constexpr long NPIX  = (long)BATCH * HW;         // 8388608
static constexpr long NTASK = NPIX / 4;                 // fallback only

static constexpr size_t LDS_BYTES = 143872;             // 128B-rounded >= LUT_N*4

// apply geometry: 256 blocks x 1024 threads == HW/4 threads exactly.
static constexpr int ABLK = 256;
static constexpr int ATHR = 1024;

// ---------------------------------------------------------------------------
// helpers (plain nontemporal IO — R7/R8 showed pinning/volatile only hurt)
// ---------------------------------------------------------------------------
__device__ __forceinline__ f32x4 ntl4(const float* p) {
    return __builtin_nontemporal_load((const f32x4*)p);
}
__device__ __forceinline__ void nts4(float* p, f32x4 v) {
    __builtin_nontemporal_store(v, (f32x4*)p);
}
__device__ __forceinline__ float d_r(unsigned n) { return (float)(n & 1023u); }
__device__ __forceinline__ float d_g(unsigned n) { return (float)((n >> 10) & 1023u); }
__device__ __forceinline__ float d_b(unsigned n) { return (float)(n >> 20); }

// gather state for one image's 4-pixel quad (32 u32 + 12 f32 = 44 VGPRs)
struct GS {
    unsigned n[4][8];
    float fr[4], fg[4], fb[4];
};

// indices + 8 LDS gathers per pixel (trunc == floor for non-negative input;
// frac computed against the clamped integer exactly like the reference)
__device__ __forceinline__ void make_gather(const unsigned* __restrict__ sl,
                                            f32x4 rc, f32x4 gc, f32x4 bc,
                                            GS& g) {
#pragma unroll
    for (int i = 0; i < 4; ++i) {
        const float scale = (float)(DIM - 1);
        float rs = rc[i] * scale, gs = gc[i] * scale, bs = bc[i] * scale;
        int ir = (int)rs; ir = ir < 0 ? 0 : (ir > DIM - 2 ? DIM - 2 : ir);
        int ig = (int)gs; ig = ig < 0 ? 0 : (ig > DIM - 2 ? DIM - 2 : ig);
        int ib = (int)bs; ib = ib < 0 ? 0 : (ib > DIM - 2 ? DIM - 2 : ib);
        g.fr[i] = rs - (float)ir;
        g.fg[i] = gs - (float)ig;
        g.fb[i] = bs - (float)ib;
        int s = ib * (DIM * DIM) + ig * DIM + ir;
        g.n[i][0] = sl[s];                     g.n[i][1] = sl[s + 1];
        g.n[i][2] = sl[s + DIM];               g.n[i][3] = sl[s + DIM + 1];
        g.n[i][4] = sl[s + DIM * DIM];         g.n[i][5] = sl[s + DIM * DIM + 1];
        g.n[i][6] = sl[s + DIM * DIM + DIM];   g.n[i][7] = sl[s + DIM * DIM + DIM + 1];
    }
}

// decode + trilinear weighted sum + dequant + nontemporal store
__device__ __forceinline__ void finish_store(const GS& g, float* __restrict__ o,
                                             float inv, float mn) {
    f32x4 orv, ogv, obv;
#pragma unroll
    for (int i = 0; i < 4; ++i) {
        float fr = g.fr[i], fg = g.fg[i], fb = g.fb[i];
        float frc = 1.0f - fr, fgc = 1.0f - fg, fbc = 1.0f - fb;
        float w00 = fbc * fgc, w01 = fbc * fg;
        float w10 = fb * fgc,  w11 = fb * fg;
        float u0 = w00 * frc, u1 = w00 * fr;
        float u2 = w01 * frc, u3 = w01 * fr;
        float u4 = w10 * frc, u5 = w10 * fr;
        float u6 = w11 * frc, u7 = w11 * fr;

        float qr = u0 * d_r(g.n[i][0]);
        qr = fmaf(u1, d_r(g.n[i][1]), qr);
        qr = fmaf(u2, d_r(g.n[i][2]), qr);
        qr = fmaf(u3, d_r(g.n[i][3]), qr);
        qr = fmaf(u4, d_r(g.n[i][4]), qr);
        qr = fmaf(u5, d_r(g.n[i][5]), qr);
        qr = fmaf(u6, d_r(g.n[i][6]), qr);
        qr = fmaf(u7, d_r(g.n[i][7]), qr);

        float qg = u0 * d_g(g.n[i][0]);
        qg = fmaf(u1, d_g(g.n[i][1]), qg);
        qg = fmaf(u2, d_g(g.n[i][2]), qg);
        qg = fmaf(u3, d_g(g.n[i][3]), qg);
        qg = fmaf(u4, d_g(g.n[i][4]), qg);
        qg = fmaf(u5, d_g(g.n[i][5]), qg);
        qg = fmaf(u6, d_g(g.n[i][6]), qg);
        qg = fmaf(u7, d_g(g.n[i][7]), qg);

        float qb = u0 * d_b(g.n[i][0]);
        qb = fmaf(u1, d_b(g.n[i][1]), qb);
        qb = fmaf(u2, d_b(g.n[i][2]), qb);
        qb = fmaf(u3, d_b(g.n[i][3]), qb);
        qb = fmaf(u4, d_b(g.n[i][4]), qb);
        qb = fmaf(u5, d_b(g.n[i][5]), qb);
        qb = fmaf(u6, d_b(g.n[i][6]), qb);
        qb = fmaf(u7, d_b(g.n[i][7]), qb);

        orv[i] = fmaf(qr, inv, mn);
        ogv[i] = fmaf(qg, inv, mn);
        obv[i] = fmaf(qb, inv, mn);
    }
    nts4(o, orv);
    nts4(o + HW, ogv);
    nts4(o + 2 * (size_t)HW, obv);
}

// ---------------------------------------------------------------------------
// Fused single kernel, 2-image jam:
//   A: per-block LUT min/max (L2-resident; order-independent => exact)
//   B: quantize LUT to u10 r|g<<10|b<<20 into LDS
//   C: 4 x { load img A,B | gather A | gather B | decode+store A | decode+store B }
//   Rationale (R2/R6/R7/R8 evidence): forced pipelines lose to regalloc; the
//   plain serial loop pays one ~700cy HBM wait PER IMAGE with phase-locked
//   waves. Jamming two images into one straight-line region amortizes that
//   wait over 2 images and doubles LDS-gather MLP, while keeping peak
//   liveness (~112 regs) inside the 128-reg cap of __launch_bounds__(1024,4).
//   No pins, no volatile — the scheduler keeps full freedom inside the region.
// ---------------------------------------------------------------------------
__global__ __launch_bounds__(1024, 4) void lut_fused(
    const float* __restrict__ x, const float* __restrict__ lut,
    float* __restrict__ out) {
    extern __shared__ unsigned sl[];
    const int t = threadIdx.x;

    const int gtid = blockIdx.x * ATHR + t;          // [0, 2^18)
    const size_t hw4 = (size_t)gtid * 4;             // [0, HW)
    const float* xp = x + hw4;
    float*       op = out + hw4;

    // ---- stage A: block-wide min/max over all 3*LUT_N floats ----
    float vmin = 1e30f, vmax = -1e30f;
    {
        const f32x4* l4 = (const f32x4*)lut;        // base is 16B-aligned
        const int NV = (3 * LUT_N) / 4;             // 26952 full float4s
#pragma unroll 4
        for (int i = t; i < NV; i += 1024) {
            f32x4 v = l4[i];
            vmin = fminf(vmin, fminf(fminf(v[0], v[1]), fminf(v[2], v[3])));
            vmax = fmaxf(vmax, fmaxf(fmaxf(v[0], v[1]), fmaxf(v[2], v[3])));
        }
        if (t < 3) {                                 // tail elems 107808..107810
            float v = lut[NV * 4 + t];
            vmin = fminf(vmin, v);
            vmax = fmaxf(vmax, v);
        }
    }
#pragma unroll
    for (int off = 32; off > 0; off >>= 1) {
        vmin = fminf(vmin, __shfl_down(vmin, off));
        vmax = fmaxf(vmax, __shfl_down(vmax, off));
    }
    float* sf = (float*)sl;
    if ((t & 63) == 0) { sf[t >> 6] = vmin; sf[16 + (t >> 6)] = vmax; }
    __syncthreads();
    float mn = sf[0], mx = sf[16];
#pragma unroll
    for (int k = 1; k < 16; ++k) {
        mn = fminf(mn, sf[k]);
        mx = fmaxf(mx, sf[16 + k]);
    }
    __syncthreads();  // all threads hold mn/mx; sl reusable

    float range = mx - mn;
    if (range < 1e-20f) range = 1e-20f;
    const float qscale = 1023.0f / range;
    const float inv    = range * (1.0f / 1023.0f);

    // ---- stage B: quantize LUT into LDS (coalesced scalar, L2-hot) ----
#pragma unroll 2
    for (int i = t; i < LUT_N; i += 1024) {
        float r = lut[i], g = lut[LUT_N + i], b = lut[2 * LUT_N + i];
        unsigned qr = (unsigned)__float2int_rn((r - mn) * qscale);
        unsigned qg = (unsigned)__float2int_rn((g - mn) * qscale);
        unsigned qb = (unsigned)__float2int_rn((b - mn) * qscale);
        sl[i] = qr | (qg << 10) | (qb << 20);
    }
    __syncthreads();

    // ---- stage C: 2-image jammed apply ----
#pragma unroll
    for (int it = 0; it < BATCH; it += 2) {
        const float* xa = xp + (size_t)it * (3 * (size_t)HW);
        const float* xb = xa + 3 * (size_t)HW;
        f32x4 ra = ntl4(xa);
        f32x4 ga = ntl4(xa + HW);
        f32x4 ba = ntl4(xa + 2 * (size_t)HW);
        f32x4 rb = ntl4(xb);
        f32x4 gb = ntl4(xb + HW);
        f32x4 bb = ntl4(xb + 2 * (size_t)HW);

        GS gA, gB;
        make_gather(sl, ra, ga, ba, gA);
        make_gather(sl, rb, gb, bb, gB);

        float* oa = op + (size_t)it * (3 * (size_t)HW);
        finish_store(gA, oa, inv, mn);
        finish_store(gB, oa + 3 * (size_t)HW, inv, mn);
    }
}

// ---------------------------------------------------------------------------
// Fallback: direct SoA gathers, exact fp32 (safety net; not dispatched).
// ---------------------------------------------------------------------------
__global__ __launch_bounds__(256) void lut_apply_soa(
    const float* __restrict__ x, const float* __restrict__ lut,
    float* __restrict__ out) {
    long t = (long)blockIdx.x * 256 + threadIdx.x;
    long p = t * 4;
    int  b  = (int)(p >> 20);
    int  hw = (int)(p & (HW - 1));
    size_t base = (size_t)b * (3 * (size_t)HW) + (size_t)hw;

    float4 rv = *(const float4*)(x + base);
    float4 gv = *(const float4*)(x + base + (size_t)HW);
    float4 bv = *(const float4*)(x + base + 2 * (size_t)HW);

    float rr[4] = {rv.x, rv.y, rv.z, rv.w};
    float gg[4] = {gv.x, gv.y, gv.z, gv.w};
    float bb[4] = {bv.x, bv.y, bv.z, bv.w};
    float orr[4], org[4], orb[4];

#pragma unroll
    for (int i = 0; i < 4; ++i) {
        const float scale = (float)(DIM - 1);
        float rs = rr[i] * scale, gs = gg[i] * scale, bs = bb[i] * scale;
        int ir = (int)floorf(rs); ir = ir < 0 ? 0 : (ir > DIM - 2 ? DIM - 2 : ir);
        int ig = (int)floorf(gs); ig = ig < 0 ? 0 : (ig > DIM - 2 ? DIM - 2 : ig);
        int ib = (int)floorf(bs); ib = ib < 0 ? 0 : (ib > DIM - 2 ? DIM - 2 : ib);
        float fr = rs - (float)ir, fg = gs - (float)ig, fb = bs - (float)ib;
        int base_i = (ib * DIM + ig) * DIM + ir;
        float acc[3] = {0.f, 0.f, 0.f};
#pragma unroll
        for (int db = 0; db < 2; ++db) {
            float wb = db ? fb : 1.f - fb;
#pragma unroll
            for (int dg = 0; dg < 2; ++dg) {
                float wg = dg ? fg : 1.f - fg;
#pragma unroll
                for (int dr = 0; dr < 2; ++dr) {
                    float wr = dr ? fr : 1.f - fr;
                    int idx = base_i + (db * DIM + dg) * DIM + dr;
                    float w = wb * wg * wr;
                    acc[0] = fmaf(w, lut[idx], acc[0]);
                    acc[1] = fmaf(w, lut[LUT_N + idx], acc[1]);
                    acc[2] = fmaf(w, lut[2 * LUT_N + idx], acc[2]);
                }
            }
        }
        orr[i] = acc[0]; org[i] = acc[1]; orb[i] = acc[2];
    }

    *(float4*)(out + base)                  = make_float4(orr[0], orr[1], orr[2], orr[3]);
    *(float4*)(out + base + (size_t)HW)     = make_float4(org[0], org[1], org[2], org[3]);
    *(float4*)(out + base + 2 * (size_t)HW) = make_float4(orb[0], orb[1], orb[2], orb[3]);
}

extern "C" void kernel_launch(void* const* d_in, const int* in_sizes, int n_in,
                              void* d_out, int out_size, void* d_ws, size_t ws_size,
                              hipStream_t stream) {
    const float* lut = (const float*)d_in[0];
    const float* x   = (const float*)d_in[1];
    if (n_in >= 2 && in_sizes[0] > in_sizes[1]) {  // defensive: order swapped
        lut = (const float*)d_in[1];
        x   = (const float*)d_in[0];
    }
    float* out = (float*)d_out;
    (void)d_ws; (void)ws_size;

    // Allow >64KB dynamic LDS (gfx950 has 160 KiB). Host-side attr set,
    // idempotent, graph-capture safe.
    (void)hipFuncSetAttribute((const void*)lut_fused,
                              hipFuncAttributeMaxDynamicSharedMemorySize,
                              (int)LDS_BYTES);
    lut_fused<<<ABLK, ATHR, LDS_BYTES, stream>>>(x, lut, out);
}